// Round 4
// baseline (43.870 us; speedup 1.0000x reference)
//
#include <hip/hip_runtime.h>

#define BIGV 1.0e6f

__device__ __forceinline__ float wave_max64(float v) {
    #pragma unroll
    for (int s = 32; s > 0; s >>= 1)
        v = fmaxf(v, __shfl_xor(v, s, 64));
    return v;
}

// One block per (b, h), 512 threads = 8 waves. Wave c owns candidate
// offsets k = c + 8*l (k -> off: 0,+1,-1,+2,-2,... so |dx| nondecreasing
// with l). Lanes l<16 hold the per-candidate lower bounds.
// Phase 1: scan the wave's 2 nearest valid rows unconditionally.
// Phase 2: one-shot threshold (wave max of current minima), ballot a need
// mask, scan only those rows. Sound: stale threshold only over-scans.
__global__ __launch_bounds__(512, 4) void imageloss_main(
    const float* __restrict__ gt, const float* __restrict__ pred,
    float* __restrict__ ws)
{
    __shared__ float gt_s[4096];
    __shared__ float pr_s[4096];
    __shared__ float rmg[64];
    __shared__ float rmp[64];
    __shared__ float red1[512];
    __shared__ float red2[512];

    const int blk = blockIdx.x;        // 0..511
    const int b   = blk >> 6;
    const int h   = blk & 63;
    const int tid = threadIdx.x;

    const float* __restrict__ gt_b = gt   + b * 4096;
    const float* __restrict__ pr_b = pred + b * 4096;

    // Stage images to LDS; fold per-row minima (16 lanes per row).
    #pragma unroll
    for (int k = 0; k < 2; ++k) {
        int idx = tid + k * 512;               // float4 index, 16 per row
        float4 vg = ((const float4*)gt_b)[idx];
        float4 vp = ((const float4*)pr_b)[idx];
        ((float4*)gt_s)[idx] = vg;
        ((float4*)pr_s)[idx] = vp;
        float mg = fminf(fminf(vg.x, vg.y), fminf(vg.z, vg.w));
        float mp = fminf(fminf(vp.x, vp.y), fminf(vp.z, vp.w));
        #pragma unroll
        for (int s = 1; s < 16; s <<= 1) {
            mg = fminf(mg, __shfl_xor(mg, s, 64));
            mp = fminf(mp, __shfl_xor(mp, s, 64));
        }
        if ((tid & 15) == 0) {
            rmg[idx >> 4] = mg;
            rmp[idx >> 4] = mp;
        }
    }
    __syncthreads();

    const int w = tid & 63;
    const int c = tid >> 6;                    // wave 0..7
    const float wf = (float)w;

    // Per-lane candidate: lane l holds k = c + 8*l (l < 16).
    const int kcand = c + 8 * w;
    const int offc  = (kcand & 1) ? ((kcand + 1) >> 1) : -(kcand >> 1);
    const int rowc  = h + offc;
    const bool valid = (w < 16) && (kcand <= 126) && ((unsigned)rowc < 64u);
    float LB1 = 3.4e38f, LB2 = 3.4e38f;
    if (valid) {
        const int adx = offc < 0 ? -offc : offc;
        const float dpl = (float)(adx + 1);
        LB1 = dpl * rmp[rowc];   // sound lower bound, pred side
        LB2 = dpl * rmg[rowc];   // gt side
    }

    float m1 = 3.4e38f;
    float m2 = 3.4e38f;

    auto scan_row = [&](int lsel) {
        const int ksel = c + 8 * lsel;
        const int offs = (ksel & 1) ? ((ksel + 1) >> 1) : -(ksel >> 1);
        const int i    = h + offs;
        const float dx2 = (float)(offs * offs);
        const float4* __restrict__ pr4 = (const float4*)(pr_s + i * 64);
        const float4* __restrict__ gt4 = (const float4*)(gt_s + i * 64);
        #pragma unroll
        for (int j4 = 0; j4 < 16; ++j4) {
            float4 p4 = pr4[j4];   // uniform address -> broadcast ds_read_b128
            float4 g4 = gt4[j4];
            float dy0 = wf - (float)(j4 * 4 + 0);
            float dy1 = wf - (float)(j4 * 4 + 1);
            float dy2 = wf - (float)(j4 * 4 + 2);
            float dy3 = wf - (float)(j4 * 4 + 3);
            float d0 = __builtin_amdgcn_sqrtf(fmaf(dy0, dy0, dx2));
            float d1 = __builtin_amdgcn_sqrtf(fmaf(dy1, dy1, dx2));
            float d2 = __builtin_amdgcn_sqrtf(fmaf(dy2, dy2, dx2));
            float d3 = __builtin_amdgcn_sqrtf(fmaf(dy3, dy3, dx2));
            // (d+1)*x = fma(d,x,x); nested triples -> v_min3_f32
            m1 = fminf(fminf(fmaf(d0, p4.x, p4.x), fmaf(d1, p4.y, p4.y)),
                 fminf(fmaf(d2, p4.z, p4.z), fminf(fmaf(d3, p4.w, p4.w), m1)));
            m2 = fminf(fminf(fmaf(d0, g4.x, g4.x), fmaf(d1, g4.y, g4.y)),
                 fminf(fmaf(d2, g4.z, g4.z), fminf(fmaf(d3, g4.w, g4.w), m2)));
        }
    };

    unsigned long long remaining = __ballot(valid);

    // Phase 1: two nearest valid rows, unconditional.
    #pragma unroll 1
    for (int p = 0; p < 2; ++p) {
        if (!remaining) break;
        int lsel = (int)__builtin_ctzll(remaining);
        remaining &= remaining - 1;
        scan_row(lsel);
    }

    // One-shot threshold + need mask.
    const float T1 = wave_max64(m1);
    const float T2 = wave_max64(m2);
    unsigned long long need = remaining & __ballot((LB1 < T1) || (LB2 < T2));
    while (need) {
        int lsel = (int)__builtin_ctzll(need);
        need &= need - 1;
        scan_row(lsel);
    }

    red1[tid] = m1;
    red2[tid] = m2;
    __syncthreads();

    if (tid < 64) {
        float a1 = red1[w];
        float a2 = red2[w];
        #pragma unroll
        for (int q = 1; q < 8; ++q) {
            a1 = fminf(a1, red1[q * 64 + w]);
            a2 = fminf(a2, red2[q * 64 + w]);
        }

        const float g = gt_s[h * 64 + w];
        const float p = pr_s[h * 64 + w];
        const float gth = g + (1.0f - g) * BIGV;
        const float pth = p + (1.0f - p) * BIGV;

        float c1 = gth * a1;   // min_dist contribution
        float c2 = pth * a2;   // min_dist_inv contribution
        float df = g - p;
        float sq = df * df;    // loss contribution

        #pragma unroll
        for (int off = 32; off > 0; off >>= 1) {
            c1 += __shfl_down(c1, off, 64);
            c2 += __shfl_down(c2, off, 64);
            sq += __shfl_down(sq, off, 64);
        }
        if (w == 0) {
            atomicAdd(&ws[0], sq);
            atomicAdd(&ws[1], c1);
            atomicAdd(&ws[2], c2);
        }
    }
}

__global__ void imageloss_final(const float* __restrict__ ws, float* __restrict__ out)
{
    out[0] = ws[0] * (1.0f / 512.0f);
    out[1] = ws[1] * (1.0f / 32768.0f);
    out[2] = ws[2] * (1.0f / 32768.0f);
}

extern "C" void kernel_launch(void* const* d_in, const int* in_sizes, int n_in,
                              void* d_out, int out_size, void* d_ws, size_t ws_size,
                              hipStream_t stream)
{
    const float* gt   = (const float*)d_in[0];
    const float* pred = (const float*)d_in[1];
    float* out = (float*)d_out;
    float* ws  = (float*)d_ws;

    hipMemsetAsync(ws, 0, 3 * sizeof(float), stream);
    imageloss_main<<<512, 512, 0, stream>>>(gt, pred, ws);
    imageloss_final<<<1, 1, 0, stream>>>(ws, out);
}